// Round 1
// baseline (2113.535 us; speedup 1.0000x reference)
//
#include <hip/hip_runtime.h>
#include <math.h>

// Problem constants (fixed by setup_inputs)
#define NN 8192
#define DD 768
#define CC 256
#define PP 16384
#define BETA_C 1.25f   // (1 + BETA) for forward loss value
#define EPS_C 1e-12f

// ---------------------------------------------------------------------------
// Kernel 1: zq_pre = z @ W_in + b_in      [8192 x 256], K = 768
// 32 rows/block, 256 threads: ti = t>>5 (0..7), tj = t&31; each thread owns
// rows ti+8r (r=0..3) and cols tj+32s (s=0..7).
// ---------------------------------------------------------------------------
__global__ __launch_bounds__(256) void k_gemm_in(const float* __restrict__ z,
    const float* __restrict__ W, const float* __restrict__ b,
    float* __restrict__ zq)
{
    __shared__ float zt[32][132];   // K-chunk 128, pad to 132 (16B-aligned rows)
    const int t = threadIdx.x;
    const int ti = t >> 5, tj = t & 31;
    const int n0 = blockIdx.x * 32;

    float acc[4][8];
#pragma unroll
    for (int r = 0; r < 4; ++r)
#pragma unroll
        for (int s = 0; s < 8; ++s) acc[r][s] = 0.f;

    for (int k0 = 0; k0 < DD; k0 += 128) {
        __syncthreads();
        // stage z[n0..n0+32)[k0..k0+128): 1024 float4, 4 per thread
#pragma unroll
        for (int l = 0; l < 4; ++l) {
            int idx = l * 256 + t;
            int row = idx >> 5;       // 32 float4 per row
            int c4  = idx & 31;
            float4 v = *reinterpret_cast<const float4*>(
                &z[(size_t)(n0 + row) * DD + k0 + c4 * 4]);
            *reinterpret_cast<float4*>(&zt[row][c4 * 4]) = v;
        }
        __syncthreads();
        for (int k = 0; k < 128; ++k) {
            float w[8];
#pragma unroll
            for (int s = 0; s < 8; ++s) w[s] = W[(size_t)(k0 + k) * CC + tj + 32 * s];
#pragma unroll
            for (int r = 0; r < 4; ++r) {
                float a = zt[ti + 8 * r][k];
#pragma unroll
                for (int s = 0; s < 8; ++s) acc[r][s] += a * w[s];
            }
        }
    }
#pragma unroll
    for (int r = 0; r < 4; ++r)
#pragma unroll
        for (int s = 0; s < 8; ++s) {
            int col = tj + 32 * s;
            zq[(size_t)(n0 + ti + 8 * r) * CC + col] = acc[r][s] + b[col];
        }
}

// ---------------------------------------------------------------------------
// Kernel 2: row L2-normalize (rows of length 256), write sq-norm of the
// NORMALIZED row (matches reference which recomputes sums post-normalize).
// One wave per row, 4 waves/block.
// ---------------------------------------------------------------------------
__global__ __launch_bounds__(256) void k_norm(const float* __restrict__ src,
    float* __restrict__ dst, float* __restrict__ sq, int rows)
{
    const int wave = threadIdx.x >> 6;
    const int lane = threadIdx.x & 63;
    const int row = blockIdx.x * 4 + wave;
    if (row >= rows) return;
    float4 v = *reinterpret_cast<const float4*>(&src[(size_t)row * CC + lane * 4]);
    float s = v.x * v.x + v.y * v.y + v.z * v.z + v.w * v.w;
#pragma unroll
    for (int off = 32; off; off >>= 1) s += __shfl_xor(s, off, 64);
    float r = 1.0f / sqrtf(s + EPS_C);
    v.x *= r; v.y *= r; v.z *= r; v.w *= r;
    *reinterpret_cast<float4*>(&dst[(size_t)row * CC + lane * 4]) = v;
    float s2 = v.x * v.x + v.y * v.y + v.z * v.z + v.w * v.w;
#pragma unroll
    for (int off = 32; off; off >>= 1) s2 += __shfl_xor(s2, off, 64);
    if (lane == 0) sq[row] = s2;
}

// ---------------------------------------------------------------------------
// Kernel 3: fused distance + argmin.
// grid (128, 4): block = 64 rows x 4096 codebook entries. 256 threads:
// ti = t>>4 (0..15), tj = t&15. Thread owns rows ti+16r, cols tj+16s (4x4).
// score = nz2[n] - 2*dot + cz2[p]; running best per thread, shuffle-reduced.
// ---------------------------------------------------------------------------
__global__ __launch_bounds__(256) void k_argmin(const float* __restrict__ zq,
    const float* __restrict__ cb, const float* __restrict__ nz2,
    const float* __restrict__ cz2, float* __restrict__ pscore,
    int* __restrict__ pidx)
{
    __shared__ float zt[64][68];
    __shared__ float ct[64][68];
    const int t = threadIdx.x;
    const int ti = t >> 4, tj = t & 15;
    const int n0 = blockIdx.x * 64;
    const int pbase = blockIdx.y * 4096;

    float bs[4];
    int bi[4];
#pragma unroll
    for (int r = 0; r < 4; ++r) { bs[r] = 3.4e38f; bi[r] = 0x7fffffff; }

    for (int pt = 0; pt < 4096; pt += 64) {
        float acc[4][4];
#pragma unroll
        for (int r = 0; r < 4; ++r)
#pragma unroll
            for (int s = 0; s < 4; ++s) acc[r][s] = 0.f;

        for (int k0 = 0; k0 < CC; k0 += 64) {
            __syncthreads();
            // stage zq tile and cb tile: 1024 float4 each, 4 per thread
#pragma unroll
            for (int l = 0; l < 4; ++l) {
                int idx = l * 256 + t;
                int row = idx >> 4;   // 16 float4 per row
                int c4  = idx & 15;
                float4 v = *reinterpret_cast<const float4*>(
                    &zq[(size_t)(n0 + row) * CC + k0 + c4 * 4]);
                *reinterpret_cast<float4*>(&zt[row][c4 * 4]) = v;
                float4 u = *reinterpret_cast<const float4*>(
                    &cb[(size_t)(pbase + pt + row) * CC + k0 + c4 * 4]);
                *reinterpret_cast<float4*>(&ct[row][c4 * 4]) = u;
            }
            __syncthreads();
#pragma unroll
            for (int k4 = 0; k4 < 16; ++k4) {
                float4 a[4], bv[4];
#pragma unroll
                for (int r = 0; r < 4; ++r)
                    a[r] = *reinterpret_cast<const float4*>(&zt[ti + 16 * r][k4 * 4]);
#pragma unroll
                for (int s = 0; s < 4; ++s)
                    bv[s] = *reinterpret_cast<const float4*>(&ct[tj + 16 * s][k4 * 4]);
#pragma unroll
                for (int r = 0; r < 4; ++r)
#pragma unroll
                    for (int s = 0; s < 4; ++s)
                        acc[r][s] += a[r].x * bv[s].x + a[r].y * bv[s].y
                                   + a[r].z * bv[s].z + a[r].w * bv[s].w;
            }
        }
        // fold into running best (scan order is ascending p => strict < keeps
        // the lowest index on ties, matching jnp.argmin)
#pragma unroll
        for (int r = 0; r < 4; ++r) {
            float nzv = nz2[n0 + ti + 16 * r];
#pragma unroll
            for (int s = 0; s < 4; ++s) {
                int p = pbase + pt + tj + 16 * s;
                float sc = nzv - 2.0f * acc[r][s] + cz2[p];
                if (sc < bs[r] || (sc == bs[r] && p < bi[r])) { bs[r] = sc; bi[r] = p; }
            }
        }
    }
    // reduce across the 16 tj lanes holding the same row
#pragma unroll
    for (int r = 0; r < 4; ++r) {
        float s = bs[r];
        int i = bi[r];
#pragma unroll
        for (int off = 8; off; off >>= 1) {
            float s2 = __shfl_xor(s, off, 64);
            int i2 = __shfl_xor(i, off, 64);
            if (s2 < s || (s2 == s && i2 < i)) { s = s2; i = i2; }
        }
        if (tj == 0) {
            int row = n0 + ti + 16 * r;
            pscore[(size_t)blockIdx.y * NN + row] = s;
            pidx[(size_t)blockIdx.y * NN + row] = i;
        }
    }
}

// ---------------------------------------------------------------------------
// Kernel 4: combine the 4 P-partition partials per row; emit idx as float
// (d_out is one flat f32 buffer) and as int for the gather kernel.
// ---------------------------------------------------------------------------
__global__ __launch_bounds__(256) void k_pick(const float* __restrict__ pscore,
    const int* __restrict__ pidx, float* __restrict__ idxf, int* __restrict__ idxi)
{
    int n = blockIdx.x * 256 + threadIdx.x;
    if (n >= NN) return;
    float bsv = pscore[n];
    int biv = pidx[n];
#pragma unroll
    for (int c = 1; c < 4; ++c) {
        float s = pscore[(size_t)c * NN + n];
        int i = pidx[(size_t)c * NN + n];
        if (s < bsv || (s == bsv && i < biv)) { bsv = s; biv = i; }
    }
    idxf[n] = (float)biv;
    idxi[n] = biv;
}

// ---------------------------------------------------------------------------
// Kernel 5: codes = cb[idx]; loss = 1.25*(zq-codes)^2; out = codes@W_out+b_out
// 16 rows/block (512 blocks), 256 threads. Thread owns cols t, t+256, t+512.
// ---------------------------------------------------------------------------
__global__ __launch_bounds__(256) void k_out(const float* __restrict__ zq,
    const float* __restrict__ cb, const int* __restrict__ idxv,
    const float* __restrict__ Wout, const float* __restrict__ bout,
    float* __restrict__ out, float* __restrict__ loss)
{
    __shared__ float codes[16][260];
    const int t = threadIdx.x;
    const int n0 = blockIdx.x * 16;

    // stage codes rows + write loss (16*64 float4 = 1024, 4 per thread)
#pragma unroll
    for (int l = 0; l < 4; ++l) {
        int idx = l * 256 + t;
        int row = idx >> 6;       // 64 float4 per row
        int c4  = idx & 63;
        int n = n0 + row;
        int p = idxv[n];
        float4 cv = *reinterpret_cast<const float4*>(&cb[(size_t)p * CC + c4 * 4]);
        *reinterpret_cast<float4*>(&codes[row][c4 * 4]) = cv;
        float4 zv = *reinterpret_cast<const float4*>(&zq[(size_t)n * CC + c4 * 4]);
        float4 lv;
        float dx = zv.x - cv.x, dy = zv.y - cv.y, dz = zv.z - cv.z, dw = zv.w - cv.w;
        lv.x = BETA_C * dx * dx; lv.y = BETA_C * dy * dy;
        lv.z = BETA_C * dz * dz; lv.w = BETA_C * dw * dw;
        *reinterpret_cast<float4*>(&loss[(size_t)n * CC + c4 * 4]) = lv;
    }
    __syncthreads();

    float acc[16][3];
#pragma unroll
    for (int i = 0; i < 16; ++i)
#pragma unroll
        for (int j = 0; j < 3; ++j) acc[i][j] = 0.f;

    for (int k = 0; k < CC; ++k) {
        float w[3];
#pragma unroll
        for (int j = 0; j < 3; ++j) w[j] = Wout[(size_t)k * DD + t + 256 * j];
#pragma unroll
        for (int i = 0; i < 16; ++i) {
            float c = codes[i][k];   // uniform address -> LDS broadcast, free
#pragma unroll
            for (int j = 0; j < 3; ++j) acc[i][j] += c * w[j];
        }
    }
#pragma unroll
    for (int i = 0; i < 16; ++i)
#pragma unroll
        for (int j = 0; j < 3; ++j)
            out[(size_t)(n0 + i) * DD + t + 256 * j] = acc[i][j] + bout[t + 256 * j];
}

// ---------------------------------------------------------------------------
extern "C" void kernel_launch(void* const* d_in, const int* in_sizes, int n_in,
                              void* d_out, int out_size, void* d_ws, size_t ws_size,
                              hipStream_t stream)
{
    const float* z        = (const float*)d_in[0];
    const float* W_in     = (const float*)d_in[1];
    const float* b_in     = (const float*)d_in[2];
    const float* W_out    = (const float*)d_in[3];
    const float* b_out    = (const float*)d_in[4];
    const float* codebook = (const float*)d_in[5];

    char* ws = (char*)d_ws;
    float* cbn  = (float*)(ws);                    // 16384*256*4 = 16,777,216
    float* zq   = (float*)(ws + 16777216);         // 8192*256*4  =  8,388,608
    float* cz2  = (float*)(ws + 25165824);         // 16384*4
    float* nz2  = (float*)(ws + 25231360);         // 8192*4
    float* psc  = (float*)(ws + 25264128);         // 4*8192*4
    int*   pix  = (int*)  (ws + 25395200);         // 4*8192*4
    int*   idxi = (int*)  (ws + 25526272);         // 8192*4

    float* out  = (float*)d_out;                       // [8192,768]
    float* loss = out + (size_t)NN * DD;               // [8192,256]
    float* idxf = loss + (size_t)NN * CC;              // [8192] as f32

    k_gemm_in<<<NN / 32, 256, 0, stream>>>(z, W_in, b_in, zq);
    k_norm<<<NN / 4, 256, 0, stream>>>(zq, zq, nz2, NN);
    k_norm<<<PP / 4, 256, 0, stream>>>(codebook, cbn, cz2, PP);
    k_argmin<<<dim3(NN / 64, 4), 256, 0, stream>>>(zq, cbn, nz2, cz2, psc, pix);
    k_pick<<<NN / 256, 256, 0, stream>>>(psc, pix, idxf, idxi);
    k_out<<<NN / 16, 256, 0, stream>>>(zq, cbn, idxi, W_out, b_out, out, loss);
}

// Round 2
// 506.272 us; speedup vs baseline: 4.1747x; 4.1747x over previous
//
#include <hip/hip_runtime.h>
#include <math.h>

#define NN 8192
#define DD 768
#define CC 256
#define PP 16384
#define NG 256           // 64-wide codebook groups per row
#define MARGIN 0.024f    // > 2*(bf16 dot error bound ~0.0044*2) with slack
#define BETA_C 1.25f
#define EPS_C 1e-12f

typedef __attribute__((ext_vector_type(8))) short bf16x8;
typedef __attribute__((ext_vector_type(4))) float f32x4;

// ---------------------------------------------------------------------------
// Kernel 1: zq_pre = z @ W_in + b_in   [8192 x 256], K=768  (f32 vector GEMM)
// ---------------------------------------------------------------------------
__global__ __launch_bounds__(256) void k_gemm_in(const float* __restrict__ z,
    const float* __restrict__ W, const float* __restrict__ b,
    float* __restrict__ zq)
{
    __shared__ float zt[32][132];
    const int t = threadIdx.x;
    const int ti = t >> 5, tj = t & 31;
    const int n0 = blockIdx.x * 32;

    float acc[4][8];
#pragma unroll
    for (int r = 0; r < 4; ++r)
#pragma unroll
        for (int s = 0; s < 8; ++s) acc[r][s] = 0.f;

    for (int k0 = 0; k0 < DD; k0 += 128) {
        __syncthreads();
#pragma unroll
        for (int l = 0; l < 4; ++l) {
            int idx = l * 256 + t;
            int row = idx >> 5;
            int c4  = idx & 31;
            float4 v = *reinterpret_cast<const float4*>(
                &z[(size_t)(n0 + row) * DD + k0 + c4 * 4]);
            *reinterpret_cast<float4*>(&zt[row][c4 * 4]) = v;
        }
        __syncthreads();
        for (int k = 0; k < 128; ++k) {
            float w[8];
#pragma unroll
            for (int s = 0; s < 8; ++s) w[s] = W[(size_t)(k0 + k) * CC + tj + 32 * s];
#pragma unroll
            for (int r = 0; r < 4; ++r) {
                float a = zt[ti + 8 * r][k];
#pragma unroll
                for (int s = 0; s < 8; ++s) acc[r][s] += a * w[s];
            }
        }
    }
#pragma unroll
    for (int r = 0; r < 4; ++r)
#pragma unroll
        for (int s = 0; s < 8; ++s) {
            int col = tj + 32 * s;
            zq[(size_t)(n0 + ti + 8 * r) * CC + col] = acc[r][s] + b[col];
        }
}

// ---------------------------------------------------------------------------
// Kernel 2: row L2-normalize; emit f32 (optional), bf16 (RNE), sq-norm of the
// normalized row, and optional 1/norm. One wave per row.
// ---------------------------------------------------------------------------
__global__ __launch_bounds__(256) void k_norm2(const float* __restrict__ src,
    float* __restrict__ dstf32, ushort* __restrict__ dstb16,
    float* __restrict__ sq, float* __restrict__ rinvout, int rows)
{
    const int wave = threadIdx.x >> 6;
    const int lane = threadIdx.x & 63;
    const int row = blockIdx.x * 4 + wave;
    if (row >= rows) return;
    float4 v = *reinterpret_cast<const float4*>(&src[(size_t)row * CC + lane * 4]);
    float s = v.x * v.x + v.y * v.y + v.z * v.z + v.w * v.w;
#pragma unroll
    for (int off = 32; off; off >>= 1) s += __shfl_xor(s, off, 64);
    float r = 1.0f / sqrtf(s + EPS_C);
    v.x *= r; v.y *= r; v.z *= r; v.w *= r;
    if (dstf32)
        *reinterpret_cast<float4*>(&dstf32[(size_t)row * CC + lane * 4]) = v;
    // bf16 round-to-nearest-even
    ushort4 hv;
    {
        unsigned ux = __float_as_uint(v.x); hv.x = (ushort)((ux + 0x7fffu + ((ux >> 16) & 1u)) >> 16);
        unsigned uy = __float_as_uint(v.y); hv.y = (ushort)((uy + 0x7fffu + ((uy >> 16) & 1u)) >> 16);
        unsigned uz = __float_as_uint(v.z); hv.z = (ushort)((uz + 0x7fffu + ((uz >> 16) & 1u)) >> 16);
        unsigned uw = __float_as_uint(v.w); hv.w = (ushort)((uw + 0x7fffu + ((uw >> 16) & 1u)) >> 16);
    }
    *reinterpret_cast<ushort4*>(&dstb16[(size_t)row * CC + lane * 4]) = hv;
    float s2 = v.x * v.x + v.y * v.y + v.z * v.z + v.w * v.w;
#pragma unroll
    for (int off = 32; off; off >>= 1) s2 += __shfl_xor(s2, off, 64);
    if (lane == 0) {
        sq[row] = s2;
        if (rinvout) rinvout[row] = r;
    }
}

// ---------------------------------------------------------------------------
// Kernel 3: approx distances via bf16 MFMA; per-(row, 64-col group) min.
// Block tile 128x128, 4 waves 2x2, wave tile 64x64 (4x4 MFMA 16x16x32).
// gmin[row][group] = min over group of (nz2 - 2*dot_bf16 + cz2).
// ---------------------------------------------------------------------------
__global__ __launch_bounds__(256) void k_dist_approx(
    const ushort* __restrict__ zqb, const ushort* __restrict__ cbb,
    const float* __restrict__ nz2, const float* __restrict__ cz2,
    float* __restrict__ gmin)
{
    __shared__ ushort lA[128][72];   // pad 8 bf16 -> 2-way-max bank aliasing
    __shared__ ushort lB[128][72];
    const int t = threadIdx.x;
    const int lane = t & 63;
    const int w = t >> 6;
    const int wr = w >> 1, wc = w & 1;
    const int n0 = blockIdx.x * 128;
    const int p0 = blockIdx.y * 128;

    f32x4 acc[4][4];
#pragma unroll
    for (int mi = 0; mi < 4; ++mi)
#pragma unroll
        for (int ni = 0; ni < 4; ++ni) acc[mi][ni] = (f32x4){0.f, 0.f, 0.f, 0.f};

    for (int k0 = 0; k0 < CC; k0 += 64) {
        __syncthreads();
#pragma unroll
        for (int i = 0; i < 4; ++i) {
            int c = i * 256 + t;          // 0..1023
            int row = c >> 3, col8 = c & 7;
            *reinterpret_cast<uint4*>(&lA[row][col8 * 8]) =
                *reinterpret_cast<const uint4*>(&zqb[(size_t)(n0 + row) * CC + k0 + col8 * 8]);
            *reinterpret_cast<uint4*>(&lB[row][col8 * 8]) =
                *reinterpret_cast<const uint4*>(&cbb[(size_t)(p0 + row) * CC + k0 + col8 * 8]);
        }
        __syncthreads();
#pragma unroll
        for (int ks = 0; ks < 2; ++ks) {
            const int koff = ks * 32 + (lane >> 4) * 8;
            bf16x8 af[4], bfv[4];
#pragma unroll
            for (int mi = 0; mi < 4; ++mi)
                af[mi] = *reinterpret_cast<const bf16x8*>(&lA[wr * 64 + mi * 16 + (lane & 15)][koff]);
#pragma unroll
            for (int ni = 0; ni < 4; ++ni)
                bfv[ni] = *reinterpret_cast<const bf16x8*>(&lB[wc * 64 + ni * 16 + (lane & 15)][koff]);
#pragma unroll
            for (int mi = 0; mi < 4; ++mi)
#pragma unroll
                for (int ni = 0; ni < 4; ++ni)
                    acc[mi][ni] = __builtin_amdgcn_mfma_f32_16x16x32_bf16(
                        af[mi], bfv[ni], acc[mi][ni], 0, 0, 0);
        }
    }

    // epilogue: dist + per-row min over the wave's 64 cols (one 64-group)
    const int rbase = n0 + wr * 64;
    const int cbase = p0 + wc * 64;
    const int grp = cbase >> 6;
    float czv[4];
#pragma unroll
    for (int ni = 0; ni < 4; ++ni) czv[ni] = cz2[cbase + ni * 16 + (lane & 15)];
#pragma unroll
    for (int mi = 0; mi < 4; ++mi) {
#pragma unroll
        for (int reg = 0; reg < 4; ++reg) {
            int grow = rbase + mi * 16 + (lane >> 4) * 4 + reg;
            float nzv = nz2[grow];
            float m = 1e30f;
#pragma unroll
            for (int ni = 0; ni < 4; ++ni) {
                float d = nzv - 2.0f * acc[mi][ni][reg] + czv[ni];
                m = fminf(m, d);
            }
#pragma unroll
            for (int off = 1; off < 16; off <<= 1)
                m = fminf(m, __shfl_xor(m, off, 64));
            if ((lane & 15) == 0)
                gmin[(size_t)grow * NG + grp] = m;
        }
    }
}

// ---------------------------------------------------------------------------
// Kernel 4: exact pick. One block per row: m = min(gmin); rescore every group
// with gmin <= m + MARGIN in exact f32; min with lowest-index tie-break.
// ---------------------------------------------------------------------------
__global__ __launch_bounds__(256) void k_exact_pick(
    const float* __restrict__ gmin, const float* __restrict__ zqn,
    const float* __restrict__ cb_raw, const float* __restrict__ rinv,
    const float* __restrict__ nz2, const float* __restrict__ cz2,
    float* __restrict__ idxf, int* __restrict__ idxi)
{
    __shared__ float zrow[CC];
    __shared__ float red[4];
    __shared__ unsigned long long bred[4];
    __shared__ int list[NG];
    __shared__ int cnt;
    const int row = blockIdx.x;
    const int t = threadIdx.x;

    zrow[t] = zqn[(size_t)row * CC + t];
    float g = gmin[(size_t)row * NG + t];
    float m = g;
#pragma unroll
    for (int off = 1; off < 64; off <<= 1) m = fminf(m, __shfl_xor(m, off, 64));
    if ((t & 63) == 0) red[t >> 6] = m;
    if (t == 0) cnt = 0;
    __syncthreads();
    m = fminf(fminf(red[0], red[1]), fminf(red[2], red[3]));
    const float thresh = m + MARGIN;
    if (g <= thresh) { int pos = atomicAdd(&cnt, 1); list[pos] = t; }
    __syncthreads();
    const int nc = cnt;
    const float nzv = nz2[row];

    unsigned long long myb = ~0ull;
    for (int ci = (t >> 6); ci < nc; ci += 4) {
        int p = list[ci] * 64 + (t & 63);
        float rv = rinv[p];
        const float* cp = &cb_raw[(size_t)p * CC];
        float s0 = 0.f, s1 = 0.f, s2 = 0.f, s3 = 0.f;
#pragma unroll 4
        for (int k = 0; k < CC; k += 4) {
            float4 c4 = *reinterpret_cast<const float4*>(&cp[k]);
            s0 += (c4.x * rv) * zrow[k];
            s1 += (c4.y * rv) * zrow[k + 1];
            s2 += (c4.z * rv) * zrow[k + 2];
            s3 += (c4.w * rv) * zrow[k + 3];
        }
        float dot = (s0 + s1) + (s2 + s3);
        float d = nzv - 2.0f * dot + cz2[p];
        d = fmaxf(d, 0.0f);   // keep uint ordering valid (dist >= 0 in practice)
        unsigned long long pk = ((unsigned long long)__float_as_uint(d) << 32) | (unsigned)p;
        myb = myb < pk ? myb : pk;
    }
#pragma unroll
    for (int off = 1; off < 64; off <<= 1) {
        unsigned long long o = __shfl_xor(myb, off, 64);
        myb = myb < o ? myb : o;
    }
    if ((t & 63) == 0) bred[t >> 6] = myb;
    __syncthreads();
    if (t == 0) {
        unsigned long long b0 = bred[0] < bred[1] ? bred[0] : bred[1];
        unsigned long long b1 = bred[2] < bred[3] ? bred[2] : bred[3];
        unsigned long long b = b0 < b1 ? b0 : b1;
        int p = (int)(b & 0xffffffffu);
        idxf[row] = (float)p;
        idxi[row] = p;
    }
}

// ---------------------------------------------------------------------------
// Kernel 5: codes = normalize(cb[idx]) (recompute = raw*rinv);
// loss = 1.25*(zq-codes)^2; out = codes@W_out + b_out.
// ---------------------------------------------------------------------------
__global__ __launch_bounds__(256) void k_out(const float* __restrict__ zq,
    const float* __restrict__ cb_raw, const float* __restrict__ rinv,
    const int* __restrict__ idxv,
    const float* __restrict__ Wout, const float* __restrict__ bout,
    float* __restrict__ out, float* __restrict__ loss)
{
    __shared__ float codes[16][260];
    const int t = threadIdx.x;
    const int n0 = blockIdx.x * 16;

#pragma unroll
    for (int l = 0; l < 4; ++l) {
        int idx = l * 256 + t;
        int row = idx >> 6;
        int c4  = idx & 63;
        int n = n0 + row;
        int p = idxv[n];
        float rv = rinv[p];
        float4 cv = *reinterpret_cast<const float4*>(&cb_raw[(size_t)p * CC + c4 * 4]);
        cv.x *= rv; cv.y *= rv; cv.z *= rv; cv.w *= rv;
        *reinterpret_cast<float4*>(&codes[row][c4 * 4]) = cv;
        float4 zv = *reinterpret_cast<const float4*>(&zq[(size_t)n * CC + c4 * 4]);
        float4 lv;
        float dx = zv.x - cv.x, dy = zv.y - cv.y, dz = zv.z - cv.z, dw = zv.w - cv.w;
        lv.x = BETA_C * dx * dx; lv.y = BETA_C * dy * dy;
        lv.z = BETA_C * dz * dz; lv.w = BETA_C * dw * dw;
        *reinterpret_cast<float4*>(&loss[(size_t)n * CC + c4 * 4]) = lv;
    }
    __syncthreads();

    float acc[16][3];
#pragma unroll
    for (int i = 0; i < 16; ++i)
#pragma unroll
        for (int j = 0; j < 3; ++j) acc[i][j] = 0.f;

    for (int k = 0; k < CC; ++k) {
        float w[3];
#pragma unroll
        for (int j = 0; j < 3; ++j) w[j] = Wout[(size_t)k * DD + t + 256 * j];
#pragma unroll
        for (int i = 0; i < 16; ++i) {
            float c = codes[i][k];
#pragma unroll
            for (int j = 0; j < 3; ++j) acc[i][j] += c * w[j];
        }
    }
#pragma unroll
    for (int i = 0; i < 16; ++i)
#pragma unroll
        for (int j = 0; j < 3; ++j)
            out[(size_t)(n0 + i) * DD + t + 256 * j] = acc[i][j] + bout[t + 256 * j];
}

// ---------------------------------------------------------------------------
extern "C" void kernel_launch(void* const* d_in, const int* in_sizes, int n_in,
                              void* d_out, int out_size, void* d_ws, size_t ws_size,
                              hipStream_t stream)
{
    const float* z        = (const float*)d_in[0];
    const float* W_in     = (const float*)d_in[1];
    const float* b_in     = (const float*)d_in[2];
    const float* W_out    = (const float*)d_in[3];
    const float* b_out    = (const float*)d_in[4];
    const float* codebook = (const float*)d_in[5];

    char* ws = (char*)d_ws;
    float*  zq    = (float*)(ws);                       // 8,388,608
    ushort* zqb   = (ushort*)(ws + 8388608);            // 4,194,304
    ushort* cbb   = (ushort*)(ws + 12582912);           // 8,388,608
    float*  gmin  = (float*)(ws + 20971520);            // 8,388,608
    float*  nz2   = (float*)(ws + 29360128);            // 32,768
    float*  cz2   = (float*)(ws + 29392896);            // 65,536
    float*  rinv  = (float*)(ws + 29458432);            // 65,536
    int*    idxi  = (int*)  (ws + 29523968);            // 32,768

    float* out  = (float*)d_out;
    float* loss = out + (size_t)NN * DD;
    float* idxf = loss + (size_t)NN * CC;

    k_gemm_in<<<NN / 32, 256, 0, stream>>>(z, W_in, b_in, zq);
    k_norm2<<<NN / 4, 256, 0, stream>>>(zq, zq, zqb, nz2, (float*)nullptr, NN);
    k_norm2<<<PP / 4, 256, 0, stream>>>(codebook, (float*)nullptr, cbb, cz2, rinv, PP);
    k_dist_approx<<<dim3(NN / 128, PP / 128), 256, 0, stream>>>(zqb, cbb, nz2, cz2, gmin);
    k_exact_pick<<<NN, 256, 0, stream>>>(gmin, zq, codebook, rinv, nz2, cz2, idxf, idxi);
    k_out<<<NN / 16, 256, 0, stream>>>(zq, codebook, rinv, idxi, W_out, b_out, out, loss);
}

// Round 3
// 317.353 us; speedup vs baseline: 6.6599x; 1.5953x over previous
//
#include <hip/hip_runtime.h>
#include <hip/hip_fp16.h>
#include <math.h>

#define NN 8192
#define DD 768
#define CC 256
#define PP 16384
#define NG 256            // 64-wide codebook groups
#define MARGIN 5.0e-3f    // > 2*eps_dist(fp16) + quantization slack (proof in notes)
#define BETA_C 1.25f
#define EPS_C 1e-12f

typedef __attribute__((ext_vector_type(8))) _Float16 f16x8;
typedef __attribute__((ext_vector_type(4))) float f32x4;

static __device__ __forceinline__ ushort f2h(float x) {
    _Float16 h = (_Float16)x;            // RNE
    return __builtin_bit_cast(unsigned short, h);
}

// ---------------------------------------------------------------------------
// Kernel 1: zq_pre = z @ W_in + b_in  [8192x256], K=768. Tiled f32 GEMM.
// BM=64, BN=64, KC=32. Grid (128,4)=512 blocks. 256 thr: ti=t>>4 rows(4),
// tj=t&15 cols(4).
// ---------------------------------------------------------------------------
__global__ __launch_bounds__(256) void k_gemm_in(const float* __restrict__ z,
    const float* __restrict__ W, const float* __restrict__ b,
    float* __restrict__ zq)
{
    __shared__ float zt[64][36];
    __shared__ float wt[32][68];
    const int t = threadIdx.x;
    const int ti = t >> 4, tj = t & 15;
    const int n0 = blockIdx.x * 64;
    const int c0 = blockIdx.y * 64;

    f32x4 acc[4];
#pragma unroll
    for (int r = 0; r < 4; ++r) acc[r] = (f32x4){0.f, 0.f, 0.f, 0.f};

    for (int k0 = 0; k0 < DD; k0 += 32) {
        __syncthreads();
#pragma unroll
        for (int l = 0; l < 2; ++l) {
            int idx = l * 256 + t;              // 512 float4 for z-tile
            int row = idx >> 3, c4 = idx & 7;
            *reinterpret_cast<float4*>(&zt[row][c4 * 4]) =
                *reinterpret_cast<const float4*>(&z[(size_t)(n0 + row) * DD + k0 + c4 * 4]);
            int krow = idx >> 4, w4 = idx & 15; // 512 float4 for W-tile
            *reinterpret_cast<float4*>(&wt[krow][w4 * 4]) =
                *reinterpret_cast<const float4*>(&W[(size_t)(k0 + krow) * CC + c0 + w4 * 4]);
        }
        __syncthreads();
#pragma unroll
        for (int kk = 0; kk < 32; kk += 4) {
            float4 a4[4], b4[4];
#pragma unroll
            for (int r = 0; r < 4; ++r)
                a4[r] = *reinterpret_cast<const float4*>(&zt[ti * 4 + r][kk]);
#pragma unroll
            for (int q = 0; q < 4; ++q)
                b4[q] = *reinterpret_cast<const float4*>(&wt[kk + q][tj * 4]);
#pragma unroll
            for (int q = 0; q < 4; ++q)
#pragma unroll
                for (int r = 0; r < 4; ++r) {
                    float av = ((const float*)&a4[r])[q];
                    acc[r].x += av * b4[q].x;
                    acc[r].y += av * b4[q].y;
                    acc[r].z += av * b4[q].z;
                    acc[r].w += av * b4[q].w;
                }
        }
    }
#pragma unroll
    for (int r = 0; r < 4; ++r) {
        int col = c0 + tj * 4;
        float4 o;
        o.x = acc[r].x + b[col];
        o.y = acc[r].y + b[col + 1];
        o.z = acc[r].z + b[col + 2];
        o.w = acc[r].w + b[col + 3];
        *reinterpret_cast<float4*>(&zq[(size_t)(n0 + ti * 4 + r) * CC + col]) = o;
    }
}

// ---------------------------------------------------------------------------
// Kernel 2: row L2-normalize; emit f32 (optional), fp16 bits, sq-norm of
// normalized row, optional 1/norm. One wave per row.
// ---------------------------------------------------------------------------
__global__ __launch_bounds__(256) void k_norm2(const float* __restrict__ src,
    float* __restrict__ dstf32, ushort* __restrict__ dsth,
    float* __restrict__ sq, float* __restrict__ rinvout, int rows)
{
    const int wave = threadIdx.x >> 6;
    const int lane = threadIdx.x & 63;
    const int row = blockIdx.x * 4 + wave;
    if (row >= rows) return;
    float4 v = *reinterpret_cast<const float4*>(&src[(size_t)row * CC + lane * 4]);
    float s = v.x * v.x + v.y * v.y + v.z * v.z + v.w * v.w;
#pragma unroll
    for (int off = 32; off; off >>= 1) s += __shfl_xor(s, off, 64);
    float r = 1.0f / sqrtf(s + EPS_C);
    v.x *= r; v.y *= r; v.z *= r; v.w *= r;
    if (dstf32)
        *reinterpret_cast<float4*>(&dstf32[(size_t)row * CC + lane * 4]) = v;
    ushort4 hv;
    hv.x = f2h(v.x); hv.y = f2h(v.y); hv.z = f2h(v.z); hv.w = f2h(v.w);
    *reinterpret_cast<ushort4*>(&dsth[(size_t)row * CC + lane * 4]) = hv;
    float s2 = v.x * v.x + v.y * v.y + v.z * v.z + v.w * v.w;
#pragma unroll
    for (int off = 32; off; off >>= 1) s2 += __shfl_xor(s2, off, 64);
    if (lane == 0) {
        sq[row] = s2;
        if (rinvout) rinvout[row] = r;
    }
}

// ---------------------------------------------------------------------------
// Kernel 3: fp16 MFMA approx distances. Per (row, 64-group): packed u32
// (bits(d1+4) with low 6 bits = argmin col) + u64 mask of cols within
// MARGIN of the group min. Block tile 128x128, 4 waves 2x2.
// ---------------------------------------------------------------------------
__global__ __launch_bounds__(256) void k_dist(
    const ushort* __restrict__ zqh, const ushort* __restrict__ cbh,
    const float* __restrict__ nz2, const float* __restrict__ cz2,
    unsigned* __restrict__ d1i1, unsigned long long* __restrict__ maskA)
{
    __shared__ ushort lA[128][72];
    __shared__ ushort lB[128][72];
    const int t = threadIdx.x;
    const int lane = t & 63;
    const int w = t >> 6;
    const int wr = w >> 1, wc = w & 1;
    const int n0 = blockIdx.x * 128;
    const int p0 = blockIdx.y * 128;

    f32x4 acc[4][4];
#pragma unroll
    for (int mi = 0; mi < 4; ++mi)
#pragma unroll
        for (int ni = 0; ni < 4; ++ni) acc[mi][ni] = (f32x4){0.f, 0.f, 0.f, 0.f};

    for (int k0 = 0; k0 < CC; k0 += 64) {
        __syncthreads();
#pragma unroll
        for (int i = 0; i < 4; ++i) {
            int c = i * 256 + t;
            int row = c >> 3, col8 = c & 7;
            *reinterpret_cast<uint4*>(&lA[row][col8 * 8]) =
                *reinterpret_cast<const uint4*>(&zqh[(size_t)(n0 + row) * CC + k0 + col8 * 8]);
            *reinterpret_cast<uint4*>(&lB[row][col8 * 8]) =
                *reinterpret_cast<const uint4*>(&cbh[(size_t)(p0 + row) * CC + k0 + col8 * 8]);
        }
        __syncthreads();
#pragma unroll
        for (int ks = 0; ks < 2; ++ks) {
            const int koff = ks * 32 + (lane >> 4) * 8;
            f16x8 af[4], bfv[4];
#pragma unroll
            for (int mi = 0; mi < 4; ++mi)
                af[mi] = *reinterpret_cast<const f16x8*>(&lA[wr * 64 + mi * 16 + (lane & 15)][koff]);
#pragma unroll
            for (int ni = 0; ni < 4; ++ni)
                bfv[ni] = *reinterpret_cast<const f16x8*>(&lB[wc * 64 + ni * 16 + (lane & 15)][koff]);
#pragma unroll
            for (int mi = 0; mi < 4; ++mi)
#pragma unroll
                for (int ni = 0; ni < 4; ++ni)
                    acc[mi][ni] = __builtin_amdgcn_mfma_f32_16x16x32_f16(
                        af[mi], bfv[ni], acc[mi][ni], 0, 0, 0);
        }
    }

    const int rbase = n0 + wr * 64;
    const int cbase = p0 + wc * 64;
    const int grp = cbase >> 6;
    float czv[4];
#pragma unroll
    for (int ni = 0; ni < 4; ++ni) czv[ni] = cz2[cbase + ni * 16 + (lane & 15)];
#pragma unroll
    for (int mi = 0; mi < 4; ++mi) {
#pragma unroll
        for (int reg = 0; reg < 4; ++reg) {
            int grow = rbase + mi * 16 + (lane >> 4) * 4 + reg;
            float nzv = nz2[grow];
            float d[4];
            unsigned pk = 0xffffffffu;
#pragma unroll
            for (int ni = 0; ni < 4; ++ni) {
                d[ni] = nzv - 2.0f * acc[mi][ni][reg] + czv[ni];
                unsigned bb = __float_as_uint(d[ni] + 4.0f);   // d+4 > 0 always
                unsigned cand = (bb & ~63u) | (unsigned)(ni * 16 + (lane & 15));
                pk = pk < cand ? pk : cand;
            }
#pragma unroll
            for (int off = 1; off < 16; off <<= 1) {
                unsigned o = __shfl_xor(pk, off, 64);
                pk = pk < o ? pk : o;
            }
            float thr = __uint_as_float(pk | 63u) - 4.0f + MARGIN;
            unsigned long long msk = 0ull;
#pragma unroll
            for (int ni = 0; ni < 4; ++ni)
                if (d[ni] <= thr) msk |= 1ull << (ni * 16 + (lane & 15));
#pragma unroll
            for (int off = 1; off < 16; off <<= 1)
                msk |= __shfl_xor(msk, off, 64);
            if ((lane & 15) == 0) {
                d1i1[(size_t)grow * NG + grp] = pk;
                maskA[(size_t)grow * NG + grp] = msk;
            }
        }
    }
}

// ---------------------------------------------------------------------------
// Kernel 4: pick. One wave per row (4 rows/block). Global approx min ->
// thresh; rescore masked entries of candidate groups in exact f32;
// lowest-index tie-break via packed u64.
// ---------------------------------------------------------------------------
__global__ __launch_bounds__(256) void k_pick(
    const unsigned* __restrict__ d1i1, const unsigned long long* __restrict__ maskA,
    const float* __restrict__ zqn, const float* __restrict__ cb_raw,
    const float* __restrict__ rinv, const float* __restrict__ nz2,
    const float* __restrict__ cz2, float* __restrict__ idxf, int* __restrict__ idxi)
{
    __shared__ int lst[4][256];
    __shared__ int cnt[4];
    const int t = threadIdx.x;
    const int w = t >> 6;
    const int lane = t & 63;
    const int row = blockIdx.x * 4 + w;

    float4 zr = *reinterpret_cast<const float4*>(&zqn[(size_t)row * CC + lane * 4]);
    uint4 dv = *reinterpret_cast<const uint4*>(&d1i1[(size_t)row * NG + lane * 4]);

    unsigned pm = dv.x;
    pm = pm < dv.y ? pm : dv.y;
    pm = pm < dv.z ? pm : dv.z;
    pm = pm < dv.w ? pm : dv.w;
#pragma unroll
    for (int off = 1; off < 64; off <<= 1) {
        unsigned o = __shfl_xor(pm, off, 64);
        pm = pm < o ? pm : o;
    }
    const float thresh = __uint_as_float(pm & ~63u) - 4.0f + MARGIN;

    if (lane == 0) cnt[w] = 0;
    __syncthreads();
    {
        unsigned g4[4] = {dv.x, dv.y, dv.z, dv.w};
#pragma unroll
        for (int j = 0; j < 4; ++j) {
            float d1g = __uint_as_float(g4[j] & ~63u) - 4.0f;
            if (d1g <= thresh) {
                int pos = atomicAdd(&cnt[w], 1);
                lst[w][pos] = lane * 4 + j;
            }
        }
    }
    __syncthreads();

    const int nc = cnt[w];
    const float nzv = nz2[row];
    unsigned long long best = ~0ull;
    for (int ci = 0; ci < nc; ++ci) {
        int g = lst[w][ci];
        unsigned long long msk = maskA[(size_t)row * NG + g];
        while (msk) {
            int bit = __ffsll((long long)msk) - 1;
            msk &= msk - 1;
            int p = g * 64 + bit;
            float rv = rinv[p];
            float4 c4 = *reinterpret_cast<const float4*>(&cb_raw[(size_t)p * CC + lane * 4]);
            float part = (c4.x * rv) * zr.x + (c4.y * rv) * zr.y
                       + (c4.z * rv) * zr.z + (c4.w * rv) * zr.w;
#pragma unroll
            for (int off = 1; off < 64; off <<= 1) part += __shfl_xor(part, off, 64);
            float dd = nzv - 2.0f * part + cz2[p];
            dd = fmaxf(dd, 0.0f);
            unsigned long long pk = ((unsigned long long)__float_as_uint(dd) << 32) | (unsigned)p;
            best = best < pk ? best : pk;
        }
    }
    if (lane == 0) {
        int p = (int)(best & 0xffffffffu);
        idxf[row] = (float)p;
        idxi[row] = p;
    }
}

// ---------------------------------------------------------------------------
// Kernel 5: codes = cb[idx]*rinv -> ws; loss = 1.25*(zq-codes)^2 (in-place
// over the zq buffer, same-slot). One float4 per thread.
// ---------------------------------------------------------------------------
__global__ __launch_bounds__(256) void k_codes(const float* __restrict__ zqn,
    const float* __restrict__ cb_raw, const float* __restrict__ rinv,
    const int* __restrict__ idxv, float* __restrict__ codes,
    float* __restrict__ loss)
{
    int idx = blockIdx.x * 256 + threadIdx.x;     // float4 index, 524288 total
    int n = idx >> 6;
    int c4 = idx & 63;
    int p = idxv[n];
    float rv = rinv[p];
    float4 cv = *reinterpret_cast<const float4*>(&cb_raw[(size_t)p * CC + c4 * 4]);
    cv.x *= rv; cv.y *= rv; cv.z *= rv; cv.w *= rv;
    *reinterpret_cast<float4*>(&codes[(size_t)n * CC + c4 * 4]) = cv;
    float4 zv = *reinterpret_cast<const float4*>(&zqn[(size_t)n * CC + c4 * 4]);
    float4 lv;
    float dx = zv.x - cv.x, dy = zv.y - cv.y, dz = zv.z - cv.z, dw = zv.w - cv.w;
    lv.x = BETA_C * dx * dx; lv.y = BETA_C * dy * dy;
    lv.z = BETA_C * dz * dz; lv.w = BETA_C * dw * dw;
    *reinterpret_cast<float4*>(&loss[(size_t)n * CC + c4 * 4]) = lv;
}

// ---------------------------------------------------------------------------
// Kernel 6: out = codes @ W_out + b_out  [8192x768], K=256. Same GEMM
// template as k_gemm_in. Grid (128, 12).
// ---------------------------------------------------------------------------
__global__ __launch_bounds__(256) void k_gemm_out(const float* __restrict__ A,
    const float* __restrict__ W, const float* __restrict__ b,
    float* __restrict__ out)
{
    __shared__ float at[64][36];
    __shared__ float wt[32][68];
    const int t = threadIdx.x;
    const int ti = t >> 4, tj = t & 15;
    const int n0 = blockIdx.x * 64;
    const int c0 = blockIdx.y * 64;

    f32x4 acc[4];
#pragma unroll
    for (int r = 0; r < 4; ++r) acc[r] = (f32x4){0.f, 0.f, 0.f, 0.f};

    for (int k0 = 0; k0 < CC; k0 += 32) {
        __syncthreads();
#pragma unroll
        for (int l = 0; l < 2; ++l) {
            int idx = l * 256 + t;
            int row = idx >> 3, c4 = idx & 7;
            *reinterpret_cast<float4*>(&at[row][c4 * 4]) =
                *reinterpret_cast<const float4*>(&A[(size_t)(n0 + row) * CC + k0 + c4 * 4]);
            int krow = idx >> 4, w4 = idx & 15;
            *reinterpret_cast<float4*>(&wt[krow][w4 * 4]) =
                *reinterpret_cast<const float4*>(&W[(size_t)(k0 + krow) * DD + c0 + w4 * 4]);
        }
        __syncthreads();
#pragma unroll
        for (int kk = 0; kk < 32; kk += 4) {
            float4 a4[4], b4[4];
#pragma unroll
            for (int r = 0; r < 4; ++r)
                a4[r] = *reinterpret_cast<const float4*>(&at[ti * 4 + r][kk]);
#pragma unroll
            for (int q = 0; q < 4; ++q)
                b4[q] = *reinterpret_cast<const float4*>(&wt[kk + q][tj * 4]);
#pragma unroll
            for (int q = 0; q < 4; ++q)
#pragma unroll
                for (int r = 0; r < 4; ++r) {
                    float av = ((const float*)&a4[r])[q];
                    acc[r].x += av * b4[q].x;
                    acc[r].y += av * b4[q].y;
                    acc[r].z += av * b4[q].z;
                    acc[r].w += av * b4[q].w;
                }
        }
    }
#pragma unroll
    for (int r = 0; r < 4; ++r) {
        int col = c0 + tj * 4;
        float4 o;
        o.x = acc[r].x + b[col];
        o.y = acc[r].y + b[col + 1];
        o.z = acc[r].z + b[col + 2];
        o.w = acc[r].w + b[col + 3];
        *reinterpret_cast<float4*>(&out[(size_t)(n0 + ti * 4 + r) * DD + col]) = o;
    }
}

// ---------------------------------------------------------------------------
extern "C" void kernel_launch(void* const* d_in, const int* in_sizes, int n_in,
                              void* d_out, int out_size, void* d_ws, size_t ws_size,
                              hipStream_t stream)
{
    const float* z        = (const float*)d_in[0];
    const float* W_in     = (const float*)d_in[1];
    const float* b_in     = (const float*)d_in[2];
    const float* W_out    = (const float*)d_in[3];
    const float* b_out    = (const float*)d_in[4];
    const float* codebook = (const float*)d_in[5];

    char* ws = (char*)d_ws;
    ushort* zqh   = (ushort*)(ws);                      //  4,194,304
    ushort* cbh   = (ushort*)(ws + 4194304);            //  8,388,608
    float*  codes = (float*)(ws + 12582912);            //  8,388,608
    float*  nz2   = (float*)(ws + 20971520);            //     32,768
    float*  cz2   = (float*)(ws + 21004288);            //     65,536
    float*  rinv  = (float*)(ws + 21069824);            //     65,536
    int*    idxi  = (int*)  (ws + 21135360);            //     32,768

    float* out  = (float*)d_out;                        // [8192x768]
    float* loss = out + (size_t)NN * DD;                // [8192x256]
    float* idxf = loss + (size_t)NN * CC;               // [8192]

    // scratch aliased into the (as yet unwritten) `out` region:
    unsigned* d1i1 = (unsigned*)d_out;                               // 8,388,608
    unsigned long long* maskA = (unsigned long long*)((char*)d_out + 8388608); // 16,777,216
    // zq (f32, normalized) lives in the `loss` region until k_codes.
    float* zq = loss;

    k_gemm_in<<<dim3(NN / 64, CC / 64), 256, 0, stream>>>(z, W_in, b_in, zq);
    k_norm2<<<NN / 4, 256, 0, stream>>>(zq, zq, zqh, nz2, (float*)nullptr, NN);
    k_norm2<<<PP / 4, 256, 0, stream>>>(codebook, (float*)nullptr, cbh, cz2, rinv, PP);
    k_dist<<<dim3(NN / 128, PP / 128), 256, 0, stream>>>(zqh, cbh, nz2, cz2, d1i1, maskA);
    k_pick<<<NN / 4, 256, 0, stream>>>(d1i1, maskA, zq, codebook, rinv, nz2, cz2, idxf, idxi);
    k_codes<<<(NN * CC / 4) / 256, 256, 0, stream>>>(zq, codebook, rinv, idxi, codes, loss);
    k_gemm_out<<<dim3(NN / 64, DD / 64), 256, 0, stream>>>(codes, W_out, b_out, out);
}

// Round 4
// 214.181 us; speedup vs baseline: 9.8680x; 1.4817x over previous
//
#include <hip/hip_runtime.h>
#include <hip/hip_fp16.h>
#include <math.h>

#define NN 8192
#define DD 768
#define CC 256
#define PP 16384
#define NG 256            // 64-wide codebook groups
#define MARGIN 5.0e-3f    // > 2*eps_dist(fp16)=2e-3, proof in R2/R4 notes
#define BETA_C 1.25f
#define EPS_C 1e-12f

typedef __attribute__((ext_vector_type(8))) _Float16 f16x8;
typedef __attribute__((ext_vector_type(4))) float f32x4;
typedef __attribute__((ext_vector_type(16))) float f32x16;

static __device__ __forceinline__ ushort f2h(float x) {
    _Float16 h = (_Float16)x;            // RNE
    return __builtin_bit_cast(unsigned short, h);
}

static __device__ __forceinline__ void gload_lds16(const void* g, void* l) {
    __builtin_amdgcn_global_load_lds(
        (const __attribute__((address_space(1))) unsigned int*)g,
        (__attribute__((address_space(3))) unsigned int*)l, 16, 0, 0);
}

// ---------------------------------------------------------------------------
// Kernel 1: zq_pre = z @ W_in + b_in  [8192x256], K=768. Tiled f32 GEMM.
// ---------------------------------------------------------------------------
__global__ __launch_bounds__(256) void k_gemm_in(const float* __restrict__ z,
    const float* __restrict__ W, const float* __restrict__ b,
    float* __restrict__ zq)
{
    __shared__ float zt[64][36];
    __shared__ float wt[32][68];
    const int t = threadIdx.x;
    const int ti = t >> 4, tj = t & 15;
    const int n0 = blockIdx.x * 64;
    const int c0 = blockIdx.y * 64;

    f32x4 acc[4];
#pragma unroll
    for (int r = 0; r < 4; ++r) acc[r] = (f32x4){0.f, 0.f, 0.f, 0.f};

    for (int k0 = 0; k0 < DD; k0 += 32) {
        __syncthreads();
#pragma unroll
        for (int l = 0; l < 2; ++l) {
            int idx = l * 256 + t;
            int row = idx >> 3, c4 = idx & 7;
            *reinterpret_cast<float4*>(&zt[row][c4 * 4]) =
                *reinterpret_cast<const float4*>(&z[(size_t)(n0 + row) * DD + k0 + c4 * 4]);
            int krow = idx >> 4, w4 = idx & 15;
            *reinterpret_cast<float4*>(&wt[krow][w4 * 4]) =
                *reinterpret_cast<const float4*>(&W[(size_t)(k0 + krow) * CC + c0 + w4 * 4]);
        }
        __syncthreads();
#pragma unroll
        for (int kk = 0; kk < 32; kk += 4) {
            float4 a4[4], b4[4];
#pragma unroll
            for (int r = 0; r < 4; ++r)
                a4[r] = *reinterpret_cast<const float4*>(&zt[ti * 4 + r][kk]);
#pragma unroll
            for (int q = 0; q < 4; ++q)
                b4[q] = *reinterpret_cast<const float4*>(&wt[kk + q][tj * 4]);
#pragma unroll
            for (int q = 0; q < 4; ++q)
#pragma unroll
                for (int r = 0; r < 4; ++r) {
                    float av = ((const float*)&a4[r])[q];
                    acc[r].x += av * b4[q].x;
                    acc[r].y += av * b4[q].y;
                    acc[r].z += av * b4[q].z;
                    acc[r].w += av * b4[q].w;
                }
        }
    }
#pragma unroll
    for (int r = 0; r < 4; ++r) {
        int col = c0 + tj * 4;
        float4 o;
        o.x = acc[r].x + b[col];
        o.y = acc[r].y + b[col + 1];
        o.z = acc[r].z + b[col + 2];
        o.w = acc[r].w + b[col + 3];
        *reinterpret_cast<float4*>(&zq[(size_t)(n0 + ti * 4 + r) * CC + col]) = o;
    }
}

// ---------------------------------------------------------------------------
// Kernel 2: row L2-normalize; optional f32 out, fp16 out, sq-norm, 1/norm.
// ---------------------------------------------------------------------------
__global__ __launch_bounds__(256) void k_norm2(const float* __restrict__ src,
    float* __restrict__ dstf32, ushort* __restrict__ dsth,
    float* __restrict__ sq, float* __restrict__ rinvout, int rows)
{
    const int wave = threadIdx.x >> 6;
    const int lane = threadIdx.x & 63;
    const int row = blockIdx.x * 4 + wave;
    if (row >= rows) return;
    float4 v = *reinterpret_cast<const float4*>(&src[(size_t)row * CC + lane * 4]);
    float s = v.x * v.x + v.y * v.y + v.z * v.z + v.w * v.w;
#pragma unroll
    for (int off = 32; off; off >>= 1) s += __shfl_xor(s, off, 64);
    float r = 1.0f / sqrtf(s + EPS_C);
    v.x *= r; v.y *= r; v.z *= r; v.w *= r;
    if (dstf32)
        *reinterpret_cast<float4*>(&dstf32[(size_t)row * CC + lane * 4]) = v;
    ushort4 hv;
    hv.x = f2h(v.x); hv.y = f2h(v.y); hv.z = f2h(v.z); hv.w = f2h(v.w);
    *reinterpret_cast<ushort4*>(&dsth[(size_t)row * CC + lane * 4]) = hv;
    if (sq) {
        float s2 = v.x * v.x + v.y * v.y + v.z * v.z + v.w * v.w;
#pragma unroll
        for (int off = 32; off; off >>= 1) s2 += __shfl_xor(s2, off, 64);
        if (lane == 0) {
            sq[row] = s2;
            if (rinvout) rinvout[row] = r;
        }
    }
}

// ---------------------------------------------------------------------------
// Kernel 3: fp16 MFMA approx. A = codebook rows (p), B = zq rows (n) =>
// C[p][n]: per lane 32 p-dists for one n (in-register min!). 32x32x16 MFMA.
// s = cz2[p] - 2*dot, computed via acc_init = -cz2/2, s = -2*acc_final.
// Per (n, 64-group): gmin float + u64 mask of entries within MARGIN.
// LDS XOR-swizzled (byte ^= (row&7)<<4), staged via global_load_lds with
// pre-swizzled global source (same involution both sides).
// ---------------------------------------------------------------------------
__global__ __launch_bounds__(256) void k_dist(
    const ushort* __restrict__ cbh, const ushort* __restrict__ zqh,
    const float* __restrict__ cz2,
    float* __restrict__ gmin, unsigned long long* __restrict__ maskA)
{
    __shared__ ushort lA[128 * 64];   // 128 p-rows x 64 f16 (128B), swizzled
    __shared__ ushort lB[128 * 64];   // 128 n-rows x 64 f16
    const int t = threadIdx.x;
    const int lane = t & 63;
    const int w = t >> 6;             // wave 0..3
    const int wr = w >> 1;            // p half (64 rows)
    const int wc = w & 1;             // n half (64 cols)
    const int p0 = blockIdx.x * 128;
    const int n0 = blockIdx.y * 128;
    const int kh = lane >> 5;         // k-half within MFMA fragment
    const int r31 = lane & 31;

    // ---- accumulator init with -cz2/2 (folds +cz2 into MFMA C) ----
    const int pb = p0 + wr * 64;
    f32x16 acc[2][2];
#pragma unroll
    for (int mi = 0; mi < 2; ++mi)
#pragma unroll
        for (int q = 0; q < 4; ++q) {
            float4 cz = *reinterpret_cast<const float4*>(
                &cz2[pb + mi * 32 + q * 8 + kh * 4]);
#pragma unroll
            for (int j = 0; j < 4; ++j) {
                float v = -0.5f * ((const float*)&cz.x)[j];
                acc[mi][0][q * 4 + j] = v;
                acc[mi][1][q * 4 + j] = v;
            }
        }

    // ---- staging setup: wave w stages rows [w*32, w*32+32) of lA and lB ----
    const int srow = lane >> 3;            // 0..7 within 8-row wave-op
    const int schunk = (lane & 7) ^ srow;  // pre-swizzled 16B-chunk index
    const char* srcA = (const char*)cbh + (size_t)(p0 + w * 32 + srow) * (CC * 2) + schunk * 16;
    const char* srcB = (const char*)zqh + (size_t)(n0 + w * 32 + srow) * (CC * 2) + schunk * 16;
    char* dstA = (char*)lA + (w * 32) * 128;
    char* dstB = (char*)lB + (w * 32) * 128;

    const char* lAc = (const char*)lA;
    const char* lBc = (const char*)lB;
    const int arow = wr * 64 + r31;
    const int brow = wc * 64 + r31;
    const int sx = (r31 & 7) << 4;         // read-side swizzle XOR

    for (int k0 = 0; k0 < CC; k0 += 64) {
        __syncthreads();                    // prev tile fully consumed
#pragma unroll
        for (int i = 0; i < 4; ++i) {
            gload_lds16(srcA + (size_t)i * 8 * (CC * 2) + k0 * 2, dstA + i * 1024);
            gload_lds16(srcB + (size_t)i * 8 * (CC * 2) + k0 * 2, dstB + i * 1024);
        }
        __syncthreads();                    // vmcnt(0) drained by compiler
#pragma unroll
        for (int ks = 0; ks < 4; ++ks) {
            const int ko = ((ks * 32 + kh * 16) ^ sx);
            f16x8 a0 = *reinterpret_cast<const f16x8*>(lAc + arow * 128 + ko);
            f16x8 a1 = *reinterpret_cast<const f16x8*>(lAc + (arow + 32) * 128 + ko);
            f16x8 b0 = *reinterpret_cast<const f16x8*>(lBc + brow * 128 + ko);
            f16x8 b1 = *reinterpret_cast<const f16x8*>(lBc + (brow + 32) * 128 + ko);
            acc[0][0] = __builtin_amdgcn_mfma_f32_32x32x16_f16(a0, b0, acc[0][0], 0, 0, 0);
            acc[0][1] = __builtin_amdgcn_mfma_f32_32x32x16_f16(a0, b1, acc[0][1], 0, 0, 0);
            acc[1][0] = __builtin_amdgcn_mfma_f32_32x32x16_f16(a1, b0, acc[1][0], 0, 0, 0);
            acc[1][1] = __builtin_amdgcn_mfma_f32_32x32x16_f16(a1, b1, acc[1][1], 0, 0, 0);
        }
    }

    // ---- epilogue: per n, group-min over 64 p's (32 in-reg + 1 shuffle) ----
    const int grp = (p0 >> 6) + wr;
#pragma unroll
    for (int ni = 0; ni < 2; ++ni) {
        float M = -1e30f;
#pragma unroll
        for (int mi = 0; mi < 2; ++mi)
#pragma unroll
            for (int r = 0; r < 16; ++r) M = fmaxf(M, acc[mi][ni][r]);
        M = fmaxf(M, __shfl_xor(M, 32, 64));
        const float thr = M - 0.5f * MARGIN;   // s<=gmin+MARGIN <=> a>=M-MARGIN/2
        unsigned long long msk = 0ull;
#pragma unroll
        for (int mi = 0; mi < 2; ++mi)
#pragma unroll
            for (int q = 0; q < 4; ++q) {
                unsigned nib = 0u;
#pragma unroll
                for (int j = 0; j < 4; ++j)
                    nib |= (acc[mi][ni][q * 4 + j] >= thr) ? (1u << j) : 0u;
                msk |= (unsigned long long)nib << (mi * 32 + q * 8 + kh * 4);
            }
        msk |= __shfl_xor(msk, 32, 64);
        if (kh == 0) {
            int n = n0 + wc * 64 + ni * 32 + r31;
            gmin[(size_t)n * NG + grp] = -2.0f * M;
            maskA[(size_t)n * NG + grp] = msk;
        }
    }
}

// ---------------------------------------------------------------------------
// Kernel 4: pick. One wave per row. Global approx min -> thresh; rescore
// masked entries of candidate groups exactly (f32, s-domain, +4 offset for
// uint ordering); lowest-index tie-break via packed u64.
// ---------------------------------------------------------------------------
__global__ __launch_bounds__(256) void k_pick(
    const float* __restrict__ gmin, const unsigned long long* __restrict__ maskA,
    const float* __restrict__ zqn, const float* __restrict__ cb_raw,
    const float* __restrict__ rinv, const float* __restrict__ cz2,
    float* __restrict__ idxf, int* __restrict__ idxi)
{
    __shared__ int lst[4][256];
    __shared__ int cnt[4];
    const int t = threadIdx.x;
    const int w = t >> 6;
    const int lane = t & 63;
    const int row = blockIdx.x * 4 + w;

    float4 zr = *reinterpret_cast<const float4*>(&zqn[(size_t)row * CC + lane * 4]);
    float4 gv = *reinterpret_cast<const float4*>(&gmin[(size_t)row * NG + lane * 4]);

    float pm = fminf(fminf(gv.x, gv.y), fminf(gv.z, gv.w));
#pragma unroll
    for (int off = 1; off < 64; off <<= 1) pm = fminf(pm, __shfl_xor(pm, off, 64));
    const float thresh = pm + MARGIN;

    if (lane == 0) cnt[w] = 0;
    __syncthreads();
    {
        const float g4[4] = {gv.x, gv.y, gv.z, gv.w};
#pragma unroll
        for (int j = 0; j < 4; ++j)
            if (g4[j] <= thresh) {
                int pos = atomicAdd(&cnt[w], 1);
                lst[w][pos] = lane * 4 + j;
            }
    }
    __syncthreads();

    const int nc = cnt[w];
    unsigned long long best = ~0ull;
    for (int ci = 0; ci < nc; ++ci) {
        int g = lst[w][ci];
        unsigned long long msk = maskA[(size_t)row * NG + g];
        while (msk) {
            int bit = __ffsll((long long)msk) - 1;
            msk &= msk - 1;
            int p = g * 64 + bit;
            float rv = rinv[p];
            float4 c4 = *reinterpret_cast<const float4*>(&cb_raw[(size_t)p * CC + lane * 4]);
            float part = (c4.x * rv) * zr.x + (c4.y * rv) * zr.y
                       + (c4.z * rv) * zr.z + (c4.w * rv) * zr.w;
#pragma unroll
            for (int off = 1; off < 64; off <<= 1) part += __shfl_xor(part, off, 64);
            float d4 = fmaf(-2.0f, part, 4.0f + cz2[p]);   // in [2,7] -> uint-orderable
            unsigned long long pk = ((unsigned long long)__float_as_uint(d4) << 32) | (unsigned)p;
            best = best < pk ? best : pk;
        }
    }
    if (lane == 0) {
        int p = (int)(best & 0xffffffffu);
        idxf[row] = (float)p;
        idxi[row] = p;
    }
}

// ---------------------------------------------------------------------------
// Kernel 5: codes = cb[idx]*rinv -> ws; loss = 1.25*(zq-codes)^2 in-place.
// ---------------------------------------------------------------------------
__global__ __launch_bounds__(256) void k_codes(const float* __restrict__ zqn,
    const float* __restrict__ cb_raw, const float* __restrict__ rinv,
    const int* __restrict__ idxv, float* __restrict__ codes,
    float* __restrict__ loss)
{
    int idx = blockIdx.x * 256 + threadIdx.x;
    int n = idx >> 6;
    int c4 = idx & 63;
    int p = idxv[n];
    float rv = rinv[p];
    float4 cv = *reinterpret_cast<const float4*>(&cb_raw[(size_t)p * CC + c4 * 4]);
    cv.x *= rv; cv.y *= rv; cv.z *= rv; cv.w *= rv;
    *reinterpret_cast<float4*>(&codes[(size_t)n * CC + c4 * 4]) = cv;
    float4 zv = *reinterpret_cast<const float4*>(&zqn[(size_t)n * CC + c4 * 4]);
    float4 lv;
    float dx = zv.x - cv.x, dy = zv.y - cv.y, dz = zv.z - cv.z, dw = zv.w - cv.w;
    lv.x = BETA_C * dx * dx; lv.y = BETA_C * dy * dy;
    lv.z = BETA_C * dz * dz; lv.w = BETA_C * dw * dw;
    *reinterpret_cast<float4*>(&loss[(size_t)n * CC + c4 * 4]) = lv;
}

// ---------------------------------------------------------------------------
// Kernel 6: out = codes @ W_out + b_out  [8192x768], K=256.
// ---------------------------------------------------------------------------
__global__ __launch_bounds__(256) void k_gemm_out(const float* __restrict__ A,
    const float* __restrict__ W, const float* __restrict__ b,
    float* __restrict__ out)
{
    __shared__ float at[64][36];
    __shared__ float wt[32][68];
    const int t = threadIdx.x;
    const int ti = t >> 4, tj = t & 15;
    const int n0 = blockIdx.x * 64;
    const int c0 = blockIdx.y * 64;

    f32x4 acc[4];
#pragma unroll
    for (int r = 0; r < 4; ++r) acc[r] = (f32x4){0.f, 0.f, 0.f, 0.f};

    for (int k0 = 0; k0 < CC; k0 += 32) {
        __syncthreads();
#pragma unroll
        for (int l = 0; l < 2; ++l) {
            int idx = l * 256 + t;
            int row = idx >> 3, c4 = idx & 7;
            *reinterpret_cast<float4*>(&at[row][c4 * 4]) =
                *reinterpret_cast<const float4*>(&A[(size_t)(n0 + row) * CC + k0 + c4 * 4]);
            int krow = idx >> 4, w4 = idx & 15;
            *reinterpret_cast<float4*>(&wt[krow][w4 * 4]) =
                *reinterpret_cast<const float4*>(&W[(size_t)(k0 + krow) * DD + c0 + w4 * 4]);
        }
        __syncthreads();
#pragma unroll
        for (int kk = 0; kk < 32; kk += 4) {
            float4 a4[4], b4[4];
#pragma unroll
            for (int r = 0; r < 4; ++r)
                a4[r] = *reinterpret_cast<const float4*>(&at[ti * 4 + r][kk]);
#pragma unroll
            for (int q = 0; q < 4; ++q)
                b4[q] = *reinterpret_cast<const float4*>(&wt[kk + q][tj * 4]);
#pragma unroll
            for (int q = 0; q < 4; ++q)
#pragma unroll
                for (int r = 0; r < 4; ++r) {
                    float av = ((const float*)&a4[r])[q];
                    acc[r].x += av * b4[q].x;
                    acc[r].y += av * b4[q].y;
                    acc[r].z += av * b4[q].z;
                    acc[r].w += av * b4[q].w;
                }
        }
    }
#pragma unroll
    for (int r = 0; r < 4; ++r) {
        int col = c0 + tj * 4;
        float4 o;
        o.x = acc[r].x + b[col];
        o.y = acc[r].y + b[col + 1];
        o.z = acc[r].z + b[col + 2];
        o.w = acc[r].w + b[col + 3];
        *reinterpret_cast<float4*>(&out[(size_t)(n0 + ti * 4 + r) * DD + col]) = o;
    }
}

// ---------------------------------------------------------------------------
extern "C" void kernel_launch(void* const* d_in, const int* in_sizes, int n_in,
                              void* d_out, int out_size, void* d_ws, size_t ws_size,
                              hipStream_t stream)
{
    const float* z        = (const float*)d_in[0];
    const float* W_in     = (const float*)d_in[1];
    const float* b_in     = (const float*)d_in[2];
    const float* W_out    = (const float*)d_in[3];
    const float* b_out    = (const float*)d_in[4];
    const float* codebook = (const float*)d_in[5];

    char* ws = (char*)d_ws;
    ushort* zqh   = (ushort*)(ws);                      //  4,194,304
    ushort* cbh   = (ushort*)(ws + 4194304);            //  8,388,608
    float*  codes = (float*)(ws + 12582912);            //  8,388,608
    float*  cz2   = (float*)(ws + 20971520);            //     65,536
    float*  rinv  = (float*)(ws + 21037056);            //     65,536
    int*    idxi  = (int*)  (ws + 21102592);            //     32,768

    float* out  = (float*)d_out;                        // [8192x768]
    float* loss = out + (size_t)NN * DD;                // [8192x256]
    float* idxf = loss + (size_t)NN * CC;               // [8192]

    // scratch aliased into the (as yet unwritten) `out` region (24 MB = fits):
    float* gmin = (float*)d_out;                                      // 8 MB
    unsigned long long* maskA = (unsigned long long*)((char*)d_out + 8388608); // 16 MB
    // zq (f32, normalized) lives in the `loss` region until k_codes.
    float* zq = loss;

    k_gemm_in<<<dim3(NN / 64, CC / 64), 256, 0, stream>>>(z, W_in, b_in, zq);
    k_norm2<<<NN / 4, 256, 0, stream>>>(zq, zq, zqh, (float*)nullptr, (float*)nullptr, NN);
    k_norm2<<<PP / 4, 256, 0, stream>>>(codebook, (float*)nullptr, cbh, cz2, rinv, PP);
    k_dist<<<dim3(PP / 128, NN / 128), 256, 0, stream>>>(cbh, zqh, cz2, gmin, maskA);
    k_pick<<<NN / 4, 256, 0, stream>>>(gmin, maskA, zq, codebook, rinv, cz2, idxf, idxi);
    k_codes<<<(NN * CC / 4) / 256, 256, 0, stream>>>(zq, codebook, rinv, idxi, codes, loss);
    k_gemm_out<<<dim3(NN / 64, DD / 64), 256, 0, stream>>>(codes, W_out, b_out, out);
}

// Round 5
// 183.204 us; speedup vs baseline: 11.5365x; 1.1691x over previous
//
#include <hip/hip_runtime.h>
#include <hip/hip_fp16.h>
#include <math.h>

#define NN 8192
#define DD 768
#define CC 256
#define PP 16384
#define NG 256            // 64-wide codebook groups
#define MARGIN 5.0e-3f    // > 2*eps_dist(fp16)=2e-3
#define BETA_C 1.25f
#define EPS_C 1e-12f

typedef __attribute__((ext_vector_type(8))) _Float16 f16x8;
typedef __attribute__((ext_vector_type(8))) short bf16x8;
typedef __attribute__((ext_vector_type(4))) float f32x4;
typedef __attribute__((ext_vector_type(16))) float f32x16;

static __device__ __forceinline__ ushort f2h(float x) {
    _Float16 h = (_Float16)x;            // RNE
    return __builtin_bit_cast(unsigned short, h);
}
static __device__ __forceinline__ ushort f2bf(float x) {
    unsigned u = __float_as_uint(x);
    return (ushort)((u + 0x7fffu + ((u >> 16) & 1u)) >> 16);
}
static __device__ __forceinline__ float bf2f(ushort h) {
    return __uint_as_float(((unsigned)h) << 16);
}

static __device__ __forceinline__ void gload_lds16(const void* g, void* l) {
    __builtin_amdgcn_global_load_lds(
        (const __attribute__((address_space(1))) unsigned int*)g,
        (__attribute__((address_space(3))) unsigned int*)l, 16, 0, 0);
}

// ---------------------------------------------------------------------------
// Kernel 1: zq_pre = z @ W_in + b_in  [8192x256], K=768. f32 (must stay
// f32-exact: feeds the argmin).
// ---------------------------------------------------------------------------
__global__ __launch_bounds__(256) void k_gemm_in(const float* __restrict__ z,
    const float* __restrict__ W, const float* __restrict__ b,
    float* __restrict__ zq)
{
    __shared__ float zt[64][36];
    __shared__ float wt[32][68];
    const int t = threadIdx.x;
    const int ti = t >> 4, tj = t & 15;
    const int n0 = blockIdx.x * 64;
    const int c0 = blockIdx.y * 64;

    f32x4 acc[4];
#pragma unroll
    for (int r = 0; r < 4; ++r) acc[r] = (f32x4){0.f, 0.f, 0.f, 0.f};

    for (int k0 = 0; k0 < DD; k0 += 32) {
        __syncthreads();
#pragma unroll
        for (int l = 0; l < 2; ++l) {
            int idx = l * 256 + t;
            int row = idx >> 3, c4 = idx & 7;
            *reinterpret_cast<float4*>(&zt[row][c4 * 4]) =
                *reinterpret_cast<const float4*>(&z[(size_t)(n0 + row) * DD + k0 + c4 * 4]);
            int krow = idx >> 4, w4 = idx & 15;
            *reinterpret_cast<float4*>(&wt[krow][w4 * 4]) =
                *reinterpret_cast<const float4*>(&W[(size_t)(k0 + krow) * CC + c0 + w4 * 4]);
        }
        __syncthreads();
#pragma unroll
        for (int kk = 0; kk < 32; kk += 4) {
            float4 a4[4], b4[4];
#pragma unroll
            for (int r = 0; r < 4; ++r)
                a4[r] = *reinterpret_cast<const float4*>(&zt[ti * 4 + r][kk]);
#pragma unroll
            for (int q = 0; q < 4; ++q)
                b4[q] = *reinterpret_cast<const float4*>(&wt[kk + q][tj * 4]);
#pragma unroll
            for (int q = 0; q < 4; ++q)
#pragma unroll
                for (int r = 0; r < 4; ++r) {
                    float av = ((const float*)&a4[r])[q];
                    acc[r].x += av * b4[q].x;
                    acc[r].y += av * b4[q].y;
                    acc[r].z += av * b4[q].z;
                    acc[r].w += av * b4[q].w;
                }
        }
    }
#pragma unroll
    for (int r = 0; r < 4; ++r) {
        int col = c0 + tj * 4;
        float4 o;
        o.x = acc[r].x + b[col];
        o.y = acc[r].y + b[col + 1];
        o.z = acc[r].z + b[col + 2];
        o.w = acc[r].w + b[col + 3];
        *reinterpret_cast<float4*>(&zq[(size_t)(n0 + ti * 4 + r) * CC + col]) = o;
    }
}

// ---------------------------------------------------------------------------
// Kernel 2: row L2-normalize; optional f32 out, fp16 out, sq-norm, 1/norm.
// ---------------------------------------------------------------------------
__global__ __launch_bounds__(256) void k_norm2(const float* __restrict__ src,
    float* __restrict__ dstf32, ushort* __restrict__ dsth,
    float* __restrict__ sq, float* __restrict__ rinvout, int rows)
{
    const int wave = threadIdx.x >> 6;
    const int lane = threadIdx.x & 63;
    const int row = blockIdx.x * 4 + wave;
    if (row >= rows) return;
    float4 v = *reinterpret_cast<const float4*>(&src[(size_t)row * CC + lane * 4]);
    float s = v.x * v.x + v.y * v.y + v.z * v.z + v.w * v.w;
#pragma unroll
    for (int off = 32; off; off >>= 1) s += __shfl_xor(s, off, 64);
    float r = 1.0f / sqrtf(s + EPS_C);
    v.x *= r; v.y *= r; v.z *= r; v.w *= r;
    if (dstf32)
        *reinterpret_cast<float4*>(&dstf32[(size_t)row * CC + lane * 4]) = v;
    ushort4 hv;
    hv.x = f2h(v.x); hv.y = f2h(v.y); hv.z = f2h(v.z); hv.w = f2h(v.w);
    *reinterpret_cast<ushort4*>(&dsth[(size_t)row * CC + lane * 4]) = hv;
    if (sq) {
        float s2 = v.x * v.x + v.y * v.y + v.z * v.z + v.w * v.w;
#pragma unroll
        for (int off = 32; off; off >>= 1) s2 += __shfl_xor(s2, off, 64);
        if (lane == 0) {
            sq[row] = s2;
            if (rinvout) rinvout[row] = r;
        }
    }
}

// ---------------------------------------------------------------------------
// Kernel 3: split W_out [256][768] f32 -> transposed hi/lo bf16 [768][256].
// ---------------------------------------------------------------------------
__global__ __launch_bounds__(256) void k_split_w(const float* __restrict__ W,
    ushort* __restrict__ wthi, ushort* __restrict__ wtlo)
{
    __shared__ float tile[64][68];
    const int t = threadIdx.x;
    const int d0 = blockIdx.x * 64;
    const int k0 = blockIdx.y * 64;
#pragma unroll
    for (int i = 0; i < 16; ++i) {
        int row = i * 4 + (t >> 6);
        int col = t & 63;
        tile[row][col] = W[(size_t)(k0 + row) * DD + d0 + col];
    }
    __syncthreads();
#pragma unroll
    for (int i = 0; i < 16; ++i) {
        int drow = i * 4 + (t >> 6);
        int kc = t & 63;
        float v = tile[kc][drow];
        ushort hi = f2bf(v);
        float rres = v - bf2f(hi);
        ushort lo = f2bf(rres);
        wthi[(size_t)(d0 + drow) * CC + k0 + kc] = hi;
        wtlo[(size_t)(d0 + drow) * CC + k0 + kc] = lo;
    }
}

// ---------------------------------------------------------------------------
// Kernel 4: fp16 MFMA approx distances. Block 256p x 128n, 4 waves:
// wr = p-half (128 rows, acc mi 0..3), wc = n-quarter... wc = n-half (64).
// Wave tile 128p x 64n = acc[4][2] of 32x32. 0.75 KB LDS per MFMA.
// s = cz2[p] - 2*dot via acc_init = -cz2/2. Outputs per (n, 64-group):
// gmin = -2*M and u64 mask of entries with s <= gmin+MARGIN.
// ---------------------------------------------------------------------------
__global__ __launch_bounds__(256) void k_dist(
    const ushort* __restrict__ cbh, const ushort* __restrict__ zqh,
    const float* __restrict__ cz2,
    float* __restrict__ gmin, unsigned long long* __restrict__ maskA)
{
    __shared__ ushort lA[256 * 64];   // 256 p-rows x 64 f16 (128B rows), swizzled
    __shared__ ushort lB[128 * 64];   // 128 n-rows x 64 f16
    const int t = threadIdx.x;
    const int lane = t & 63;
    const int w = t >> 6;             // wave 0..3
    const int wr = w >> 1;            // p half (128 rows)
    const int wc = w & 1;             // n half (64 cols)
    const int p0 = blockIdx.x * 256;
    const int n0 = blockIdx.y * 128;
    const int kh = lane >> 5;
    const int r31 = lane & 31;

    // acc init with -cz2/2
    f32x16 acc[4][2];
#pragma unroll
    for (int mi = 0; mi < 4; ++mi) {
        const int pbm = p0 + wr * 128 + mi * 32;
#pragma unroll
        for (int q = 0; q < 4; ++q) {
            float4 cz = *reinterpret_cast<const float4*>(&cz2[pbm + q * 8 + kh * 4]);
#pragma unroll
            for (int j = 0; j < 4; ++j) {
                float v = -0.5f * ((const float*)&cz.x)[j];
                acc[mi][0][q * 4 + j] = v;
                acc[mi][1][q * 4 + j] = v;
            }
        }
    }

    // staging: wave w stages lA rows [w*64, w*64+64) and lB rows [w*32, +32)
    const int srow = lane >> 3;            // 0..7
    const int schunk = (lane & 7) ^ srow;  // pre-swizzled 16B chunk
    const char* srcA = (const char*)cbh + (size_t)(p0 + w * 64 + srow) * (CC * 2) + schunk * 16;
    const char* srcB = (const char*)zqh + (size_t)(n0 + w * 32 + srow) * (CC * 2) + schunk * 16;
    char* dstA = (char*)lA + (w * 64) * 128;
    char* dstB = (char*)lB + (w * 32) * 128;

    const char* lAc = (const char*)lA;
    const char* lBc = (const char*)lB;
    const int sx = (r31 & 7) << 4;

    for (int k0 = 0; k0 < CC; k0 += 64) {
        __syncthreads();
#pragma unroll
        for (int i = 0; i < 8; ++i)
            gload_lds16(srcA + (size_t)i * 8 * (CC * 2) + k0 * 2, dstA + i * 1024);
#pragma unroll
        for (int i = 0; i < 4; ++i)
            gload_lds16(srcB + (size_t)i * 8 * (CC * 2) + k0 * 2, dstB + i * 1024);
        __syncthreads();
#pragma unroll
        for (int ks = 0; ks < 4; ++ks) {
            const int ko = ((ks * 32 + kh * 16) ^ sx);
            f16x8 af[4], bfv[2];
#pragma unroll
            for (int mi = 0; mi < 4; ++mi)
                af[mi] = *reinterpret_cast<const f16x8*>(
                    lAc + (wr * 128 + mi * 32 + r31) * 128 + ko);
#pragma unroll
            for (int ni = 0; ni < 2; ++ni)
                bfv[ni] = *reinterpret_cast<const f16x8*>(
                    lBc + (wc * 64 + ni * 32 + r31) * 128 + ko);
#pragma unroll
            for (int mi = 0; mi < 4; ++mi)
#pragma unroll
                for (int ni = 0; ni < 2; ++ni)
                    acc[mi][ni] = __builtin_amdgcn_mfma_f32_32x32x16_f16(
                        af[mi], bfv[ni], acc[mi][ni], 0, 0, 0);
        }
    }

    // epilogue: per n-frag (2), per 64-group (mi pairs), in-reg max + 1 shuffle
#pragma unroll
    for (int ni = 0; ni < 2; ++ni) {
#pragma unroll
        for (int g = 0; g < 2; ++g) {
            float M = -1e30f;
#pragma unroll
            for (int m2 = 0; m2 < 2; ++m2)
#pragma unroll
                for (int r = 0; r < 16; ++r) M = fmaxf(M, acc[g * 2 + m2][ni][r]);
            M = fmaxf(M, __shfl_xor(M, 32, 64));
            const float thr = M - 0.5f * MARGIN;
            unsigned long long msk = 0ull;
#pragma unroll
            for (int m2 = 0; m2 < 2; ++m2)
#pragma unroll
                for (int q = 0; q < 4; ++q) {
                    unsigned nib = 0u;
#pragma unroll
                    for (int j = 0; j < 4; ++j)
                        nib |= (acc[g * 2 + m2][ni][q * 4 + j] >= thr) ? (1u << j) : 0u;
                    msk |= (unsigned long long)nib << (m2 * 32 + q * 8 + kh * 4);
                }
            msk |= __shfl_xor(msk, 32, 64);
            if (kh == 0) {
                int n = n0 + wc * 64 + ni * 32 + r31;
                int grp = (p0 >> 6) + wr * 2 + g;
                gmin[(size_t)n * NG + grp] = -2.0f * M;
                maskA[(size_t)n * NG + grp] = msk;
            }
        }
    }
}

// ---------------------------------------------------------------------------
// Kernel 5: pick. One wave per row; exact f32 rescore of masked candidates.
// ---------------------------------------------------------------------------
__global__ __launch_bounds__(256) void k_pick(
    const float* __restrict__ gmin, const unsigned long long* __restrict__ maskA,
    const float* __restrict__ zqn, const float* __restrict__ cb_raw,
    const float* __restrict__ rinv, const float* __restrict__ cz2,
    float* __restrict__ idxf, int* __restrict__ idxi)
{
    __shared__ int lst[4][256];
    __shared__ int cnt[4];
    const int t = threadIdx.x;
    const int w = t >> 6;
    const int lane = t & 63;
    const int row = blockIdx.x * 4 + w;

    float4 zr = *reinterpret_cast<const float4*>(&zqn[(size_t)row * CC + lane * 4]);
    float4 gv = *reinterpret_cast<const float4*>(&gmin[(size_t)row * NG + lane * 4]);

    float pm = fminf(fminf(gv.x, gv.y), fminf(gv.z, gv.w));
#pragma unroll
    for (int off = 1; off < 64; off <<= 1) pm = fminf(pm, __shfl_xor(pm, off, 64));
    const float thresh = pm + MARGIN;

    if (lane == 0) cnt[w] = 0;
    __syncthreads();
    {
        const float g4[4] = {gv.x, gv.y, gv.z, gv.w};
#pragma unroll
        for (int j = 0; j < 4; ++j)
            if (g4[j] <= thresh) {
                int pos = atomicAdd(&cnt[w], 1);
                lst[w][pos] = lane * 4 + j;
            }
    }
    __syncthreads();

    const int nc = cnt[w];
    unsigned long long best = ~0ull;
    for (int ci = 0; ci < nc; ++ci) {
        int g = lst[w][ci];
        unsigned long long msk = maskA[(size_t)row * NG + g];
        while (msk) {
            int bit = __ffsll((long long)msk) - 1;
            msk &= msk - 1;
            int p = g * 64 + bit;
            float rv = rinv[p];
            float4 c4 = *reinterpret_cast<const float4*>(&cb_raw[(size_t)p * CC + lane * 4]);
            float part = (c4.x * rv) * zr.x + (c4.y * rv) * zr.y
                       + (c4.z * rv) * zr.z + (c4.w * rv) * zr.w;
#pragma unroll
            for (int off = 1; off < 64; off <<= 1) part += __shfl_xor(part, off, 64);
            float d4 = fmaf(-2.0f, part, 4.0f + cz2[p]);
            unsigned long long pk = ((unsigned long long)__float_as_uint(d4) << 32) | (unsigned)p;
            best = best < pk ? best : pk;
        }
    }
    if (lane == 0) {
        int p = (int)(best & 0xffffffffu);
        idxf[row] = (float)p;
        idxi[row] = p;
    }
}

// ---------------------------------------------------------------------------
// Kernel 6: codes = cb[idx]*rinv -> hi/lo bf16 split; loss = 1.25*(zq-codes)^2
// in-place over the zq (loss) buffer.
// ---------------------------------------------------------------------------
__global__ __launch_bounds__(256) void k_codes(const float* __restrict__ zqn,
    const float* __restrict__ cb_raw, const float* __restrict__ rinv,
    const int* __restrict__ idxv, ushort* __restrict__ chi,
    ushort* __restrict__ clo, float* __restrict__ loss)
{
    int idx = blockIdx.x * 256 + threadIdx.x;
    int n = idx >> 6;
    int c4 = idx & 63;
    int p = idxv[n];
    float rv = rinv[p];
    float4 cv = *reinterpret_cast<const float4*>(&cb_raw[(size_t)p * CC + c4 * 4]);
    cv.x *= rv; cv.y *= rv; cv.z *= rv; cv.w *= rv;
    ushort4 hv, lv16;
    {
        hv.x = f2bf(cv.x); lv16.x = f2bf(cv.x - bf2f(hv.x));
        hv.y = f2bf(cv.y); lv16.y = f2bf(cv.y - bf2f(hv.y));
        hv.z = f2bf(cv.z); lv16.z = f2bf(cv.z - bf2f(hv.z));
        hv.w = f2bf(cv.w); lv16.w = f2bf(cv.w - bf2f(hv.w));
    }
    *reinterpret_cast<ushort4*>(&chi[(size_t)n * CC + c4 * 4]) = hv;
    *reinterpret_cast<ushort4*>(&clo[(size_t)n * CC + c4 * 4]) = lv16;
    float4 zv = *reinterpret_cast<const float4*>(&zqn[(size_t)n * CC + c4 * 4]);
    float4 lsv;
    float dx = zv.x - cv.x, dy = zv.y - cv.y, dz = zv.z - cv.z, dw = zv.w - cv.w;
    lsv.x = BETA_C * dx * dx; lsv.y = BETA_C * dy * dy;
    lsv.z = BETA_C * dz * dz; lsv.w = BETA_C * dw * dw;
    *reinterpret_cast<float4*>(&loss[(size_t)n * CC + c4 * 4]) = lsv;
}

// ---------------------------------------------------------------------------
// Kernel 7: out = codes @ W_out + b_out via split-bf16 MFMA
// (hi*hi + hi*lo + lo*hi). Block 128n x 128d, 4 waves 2x2, wave 64x64.
// ---------------------------------------------------------------------------
__global__ __launch_bounds__(256) void k_gemm_out_mfma(
    const ushort* __restrict__ chi, const ushort* __restrict__ clo,
    const ushort* __restrict__ wthi, const ushort* __restrict__ wtlo,
    const float* __restrict__ bout, float* __restrict__ out)
{
    __shared__ ushort sAh[128 * 64];
    __shared__ ushort sAl[128 * 64];
    __shared__ ushort sBh[128 * 64];
    __shared__ ushort sBl[128 * 64];
    const int t = threadIdx.x;
    const int lane = t & 63;
    const int w = t >> 6;
    const int wr = w >> 1;            // n half
    const int wc = w & 1;             // d half
    const int nb = blockIdx.x * 128;
    const int db = blockIdx.y * 128;
    const int kh = lane >> 5;
    const int r31 = lane & 31;

    f32x16 acc[2][2];
#pragma unroll
    for (int mi = 0; mi < 2; ++mi)
#pragma unroll
        for (int ni = 0; ni < 2; ++ni)
#pragma unroll
            for (int r = 0; r < 16; ++r) acc[mi][ni][r] = 0.f;

    const int srow = lane >> 3;
    const int schunk = (lane & 7) ^ srow;
    const size_t rowA = (size_t)(nb + w * 32 + srow) * CC;
    const size_t rowB = (size_t)(db + w * 32 + srow) * CC;
    const char* sAhsrc = (const char*)chi + rowA * 2 + schunk * 16;
    const char* sAlsrc = (const char*)clo + rowA * 2 + schunk * 16;
    const char* sBhsrc = (const char*)wthi + rowB * 2 + schunk * 16;
    const char* sBlsrc = (const char*)wtlo + rowB * 2 + schunk * 16;
    char* dA = (char*)sAh + (w * 32) * 128;
    char* dAl = (char*)sAl + (w * 32) * 128;
    char* dB = (char*)sBh + (w * 32) * 128;
    char* dBl = (char*)sBl + (w * 32) * 128;

    const int sx = (r31 & 7) << 4;

    for (int k0 = 0; k0 < CC; k0 += 64) {
        __syncthreads();
#pragma unroll
        for (int i = 0; i < 4; ++i) {
            gload_lds16(sAhsrc + (size_t)i * 8 * (CC * 2) + k0 * 2, dA + i * 1024);
            gload_lds16(sAlsrc + (size_t)i * 8 * (CC * 2) + k0 * 2, dAl + i * 1024);
            gload_lds16(sBhsrc + (size_t)i * 8 * (CC * 2) + k0 * 2, dB + i * 1024);
            gload_lds16(sBlsrc + (size_t)i * 8 * (CC * 2) + k0 * 2, dBl + i * 1024);
        }
        __syncthreads();
#pragma unroll
        for (int ks = 0; ks < 4; ++ks) {
            const int ko = ((ks * 32 + kh * 16) ^ sx);
            bf16x8 ah[2], al[2], bh[2], bl[2];
#pragma unroll
            for (int mi = 0; mi < 2; ++mi) {
                ah[mi] = *reinterpret_cast<const bf16x8*>(
                    (const char*)sAh + (wr * 64 + mi * 32 + r31) * 128 + ko);
                al[mi] = *reinterpret_cast<const bf16x8*>(
                    (const char*)sAl + (wr * 64 + mi * 32 + r31) * 128 + ko);
            }
#pragma unroll
            for (int ni = 0; ni < 2; ++ni) {
                bh[ni] = *reinterpret_cast<const bf16x8*>(
                    (const char*)sBh + (wc * 64 + ni * 32 + r31) * 128 + ko);
                bl[ni] = *reinterpret_cast<const bf16x8*>(
                    (const char*)sBl + (wc * 64 + ni * 32 + r31) * 128 + ko);
            }
#pragma unroll
            for (int mi = 0; mi < 2; ++mi)
#pragma unroll
                for (int ni = 0; ni < 2; ++ni) {
                    acc[mi][ni] = __builtin_amdgcn_mfma_f32_32x32x16_bf16(
                        ah[mi], bh[ni], acc[mi][ni], 0, 0, 0);
                    acc[mi][ni] = __builtin_amdgcn_mfma_f32_32x32x16_bf16(
                        ah[mi], bl[ni], acc[mi][ni], 0, 0, 0);
                    acc[mi][ni] = __builtin_amdgcn_mfma_f32_32x32x16_bf16(
                        al[mi], bh[ni], acc[mi][ni], 0, 0, 0);
                }
        }
    }

    // epilogue: out[n][d] = acc + bias
#pragma unroll
    for (int ni = 0; ni < 2; ++ni) {
        const int d = db + wc * 64 + ni * 32 + r31;
        const float bv = bout[d];
#pragma unroll
        for (int mi = 0; mi < 2; ++mi) {
            const int nbase = nb + wr * 64 + mi * 32 + 4 * kh;
#pragma unroll
            for (int q = 0; q < 4; ++q)
#pragma unroll
                for (int j = 0; j < 4; ++j) {
                    int n = nbase + j + 8 * q;
                    out[(size_t)n * DD + d] = acc[mi][ni][q * 4 + j] + bv;
                }
        }
    }
}

// ---------------------------------------------------------------------------
extern "C" void kernel_launch(void* const* d_in, const int* in_sizes, int n_in,
                              void* d_out, int out_size, void* d_ws, size_t ws_size,
                              hipStream_t stream)
{
    const float* z        = (const float*)d_in[0];
    const float* W_in     = (const float*)d_in[1];
    const float* b_in     = (const float*)d_in[2];
    const float* W_out    = (const float*)d_in[3];
    const float* b_out    = (const float*)d_in[4];
    const float* codebook = (const float*)d_in[5];

    char* ws = (char*)d_ws;
    ushort* zqh   = (ushort*)(ws);                      //  4,194,304
    ushort* cbh   = (ushort*)(ws + 4194304);            //  8,388,608
    ushort* chi   = (ushort*)(ws + 12582912);           //  4,194,304
    ushort* clo   = (ushort*)(ws + 16777216);           //  4,194,304
    ushort* wthi  = (ushort*)(ws + 20971520);           //    393,216
    ushort* wtlo  = (ushort*)(ws + 21364736);           //    393,216
    float*  cz2   = (float*)(ws + 21757952);            //     65,536
    float*  rinv  = (float*)(ws + 21823488);            //     65,536
    int*    idxi  = (int*)  (ws + 21889024);            //     32,768

    float* out  = (float*)d_out;                        // [8192x768]
    float* loss = out + (size_t)NN * DD;                // [8192x256]
    float* idxf = loss + (size_t)NN * CC;               // [8192]

    // scratch aliased into the (unwritten) `out` region (24 MB <= 25.2 MB):
    float* gmin = (float*)d_out;                                      // 8 MB
    unsigned long long* maskA = (unsigned long long*)((char*)d_out + 8388608); // 16 MB
    // zq (f32, normalized) lives in the `loss` region until k_codes.
    float* zq = loss;

    k_gemm_in<<<dim3(NN / 64, CC / 64), 256, 0, stream>>>(z, W_in, b_in, zq);
    k_norm2<<<NN / 4, 256, 0, stream>>>(zq, zq, zqh, (float*)nullptr, (float*)nullptr, NN);
    k_norm2<<<PP / 4, 256, 0, stream>>>(codebook, (float*)nullptr, cbh, cz2, rinv, PP);
    k_split_w<<<dim3(DD / 64, CC / 64), 256, 0, stream>>>(W_out, wthi, wtlo);
    k_dist<<<dim3(PP / 256, NN / 128), 256, 0, stream>>>(cbh, zqh, cz2, gmin, maskA);
    k_pick<<<NN / 4, 256, 0, stream>>>(gmin, maskA, zq, codebook, rinv, cz2, idxf, idxi);
    k_codes<<<(NN * CC / 4) / 256, 256, 0, stream>>>(zq, codebook, rinv, idxi, chi, clo, loss);
    k_gemm_out_mfma<<<dim3(NN / 128, DD / 128), 256, 0, stream>>>(chi, clo, wthi, wtlo, b_out, out);
}